// Round 1
// baseline (4509.218 us; speedup 1.0000x reference)
//
#include <hip/hip_runtime.h>
#include <stdint.h>

typedef __attribute__((ext_vector_type(4))) float f32x4;
typedef __attribute__((ext_vector_type(8))) short bf16x8;
typedef __attribute__((ext_vector_type(4))) unsigned int u32x4;
typedef __attribute__((ext_vector_type(2))) unsigned int u32x2;
typedef __attribute__((ext_vector_type(4))) unsigned short u16x4;
typedef unsigned short ushort_t;

#define B_N 32
#define T_N 1024
#define D_N 512
#define H_N 512
#define G4H 2048

__device__ __forceinline__ ushort_t f2bf(float f) {
    union { float f; unsigned int u; } v; v.f = f;
    unsigned int r = v.u + 0x7FFFu + ((v.u >> 16) & 1u);   // RNE
    return (ushort_t)(r >> 16);
}
__device__ __forceinline__ float bf2f(ushort_t b) {
    union { unsigned int u; float f; } v; v.u = ((unsigned int)b) << 16;
    return v.f;
}

// ---------------------------------------------------------------------------
// prep: fp32 -> bf16 conversion of x, W_ih, W_hh; bias_sum = b_ih+b_hh;
//       zero sync counters (must happen every launch: ws persists across
//       graph replays).
// ---------------------------------------------------------------------------
__global__ __launch_bounds__(256) void prep_kernel(
    const float* __restrict__ x, const float* __restrict__ wih,
    const float* __restrict__ whh, const float* __restrict__ bih,
    const float* __restrict__ bhh,
    ushort_t* __restrict__ xb, ushort_t* __restrict__ wihb,
    ushort_t* __restrict__ whhb, float* __restrict__ bias,
    int* __restrict__ cnt)
{
    size_t i = (size_t)blockIdx.x * 256 + threadIdx.x;
    if (i < 2048) { bias[i] = bih[i] + bhh[i]; cnt[i] = 0; }
    const size_t NX = (size_t)B_N * T_N * D_N / 4;   // 4194304 quads
    const size_t NW = (size_t)G4H * D_N / 4;         // 262144 quads
    if (i < NX) {
        f32x4 v = ((const f32x4*)x)[i];
        u16x4 o; o[0]=f2bf(v[0]); o[1]=f2bf(v[1]); o[2]=f2bf(v[2]); o[3]=f2bf(v[3]);
        ((u16x4*)xb)[i] = o;
    } else if (i < NX + NW) {
        size_t j = i - NX;
        f32x4 v = ((const f32x4*)wih)[j];
        u16x4 o; o[0]=f2bf(v[0]); o[1]=f2bf(v[1]); o[2]=f2bf(v[2]); o[3]=f2bf(v[3]);
        ((u16x4*)wihb)[j] = o;
    } else if (i < NX + 2 * NW) {
        size_t j = i - NX - NW;
        f32x4 v = ((const f32x4*)whh)[j];
        u16x4 o; o[0]=f2bf(v[0]); o[1]=f2bf(v[1]); o[2]=f2bf(v[2]); o[3]=f2bf(v[3]);
        ((u16x4*)whhb)[j] = o;
    }
}

// ---------------------------------------------------------------------------
// xg = x @ W_ih^T + (b_ih+b_hh), stored bf16 as [T][4H][B] so the recurrence
// accumulator init is a contiguous 8B load per lane.
// Block = (t-chunk of 8) x (gate-chunk of 128), 8 waves; wave w owns M-tile w.
// ---------------------------------------------------------------------------
__global__ __launch_bounds__(512) void xg_gemm(
    const ushort_t* __restrict__ xb,    // [B][T][D] bf16
    const ushort_t* __restrict__ wihb,  // [4H][D] bf16
    const float* __restrict__ bias,     // [4H]
    ushort_t* __restrict__ xg)          // [T][4H][B] bf16
{
    int blk = blockIdx.x;
    int tc = blk >> 4;          // 0..127 (t-chunk of 8)
    int gb = blk & 15;          // 0..15  (gate-chunk of 128)
    int w  = threadIdx.x >> 6;  // wave 0..7
    int l  = threadIdx.x & 63;
    int lr = l & 15;
    int lk = l >> 4;

    int arow = gb * 128 + w * 16 + lr;                 // W_ih row (gate col)
    const ushort_t* ap = wihb + (size_t)arow * D_N;

    f32x4 acc[16];
#pragma unroll
    for (int i = 0; i < 16; ++i) { acc[i][0]=0.f; acc[i][1]=0.f; acc[i][2]=0.f; acc[i][3]=0.f; }

#pragma unroll
    for (int kk = 0; kk < 16; ++kk) {
        bf16x8 af = *(const bf16x8*)(ap + kk * 32 + lk * 8);
#pragma unroll
        for (int nn = 0; nn < 16; ++nn) {
            int tl = nn >> 1, bh = nn & 1;
            int bcol = bh * 16 + lr;
            int t = tc * 8 + tl;
            bf16x8 bf = *(const bf16x8*)(xb + ((size_t)bcol * T_N + t) * D_N + kk * 32 + lk * 8);
            acc[nn] = __builtin_amdgcn_mfma_f32_16x16x32_bf16(af, bf, acc[nn], 0, 0, 0);
        }
    }

    float bs[4];
#pragma unroll
    for (int j = 0; j < 4; ++j) bs[j] = bias[gb * 128 + w * 16 + lk * 4 + j];

#pragma unroll
    for (int nn = 0; nn < 16; ++nn) {
        int tl = nn >> 1, bh = nn & 1;
        int bcol = bh * 16 + lr;
        int t = tc * 8 + tl;
#pragma unroll
        for (int j = 0; j < 4; ++j) {
            int r = gb * 128 + w * 16 + lk * 4 + j;
            xg[((size_t)t * G4H + r) * B_N + bcol] = f2bf(acc[nn][j] + bs[j]);
        }
    }
}

// ---------------------------------------------------------------------------
// Sequential LSTM recurrence.
// 64 blocks x 256 threads. Block b: group g = b>>5 (batches 16g..16g+15),
// slice s = b&31 (h columns 16s..16s+15 -> gate cols {q*512 + 16s..} q=0..3).
// Wave w computes gate-q=w tile [16 batches x 16 cols] via MFMA; W_hh slice
// lives in registers. h is exchanged through a device-coherent (sc0 sc1)
// ring buffer; per-step monotonic atomic counters provide the group barrier.
// ---------------------------------------------------------------------------
__global__ __launch_bounds__(256) void lstm_rec(
    const ushort_t* __restrict__ xg,    // [T][4H][B] bf16 (bias folded)
    const ushort_t* __restrict__ whhb,  // [4H][H] bf16
    ushort_t* __restrict__ ring,        // [2][2][16][512] bf16
    int* __restrict__ cnt,              // [2][1024]
    float* __restrict__ out,            // [B][T][H]
    float* __restrict__ hn,             // [B][H]
    float* __restrict__ cn)             // [B][H]
{
    const int tid = threadIdx.x;
    const int g = blockIdx.x >> 5;
    const int s = blockIdx.x & 31;
    const int w = tid >> 6, l = tid & 63, lr = l & 15, lk = l >> 4;

    __shared__ float glds[4][16][16];   // [gate][batch][col]

    // ---- persistent W_hh fragments (B operand): lane lr -> gate col
    const int gc = w * 512 + s * 16 + lr;
    bf16x8 wfrag[16];
#pragma unroll
    for (int kk = 0; kk < 16; ++kk)
        wfrag[kk] = *(const bf16x8*)(whhb + (size_t)gc * H_N + kk * 32 + lk * 8);

    // ---- elementwise identity
    const int eb = tid >> 4;      // batch within group
    const int ej = tid & 15;      // col within slice
    float c_reg = 0.f;
    float* outp = out + ((size_t)(g * 16 + eb)) * T_N * H_N + s * 16 + ej;
    ushort_t* rp_base = ring + (size_t)eb * H_N + s * 16 + ej;  // + parity/group offset per t
    const ushort_t* xgp = xg + (size_t)gc * B_N + g * 16 + lk * 4;
    int* cntg = cnt + g * 1024;

    for (int t = 0; t < T_N; ++t) {
        // prefetch xg tile (independent of h -> overlaps the poll)
        u32x2 xv = *(const u32x2*)(xgp + (size_t)t * (G4H * B_N));
        union { u32x2 u; ushort_t s4[4]; } xu; xu.u = xv;
        f32x4 acc0, acc1;
#pragma unroll
        for (int j = 0; j < 4; ++j) { acc0[j] = bf2f(xu.s4[j]); acc1[j] = 0.f; }

        if (t > 0) {
            // ---- group barrier: wait for all 32 WGs' h of step t-1
            if (tid == 0) {
                int spins = 0;
                while (__hip_atomic_load(&cntg[t - 1], __ATOMIC_RELAXED,
                                         __HIP_MEMORY_SCOPE_AGENT) < 32) {
                    if (++spins > (1 << 22)) break;   // safety valve (never hit)
                }
            }
            __syncthreads();

            // ---- load A fragments (h[t-1]) coherently, single asm block
            const ushort_t* hrow = ring + ((size_t)((t - 1) & 1) * 2 + g) * (16 * 512)
                                   + (size_t)lr * H_N + lk * 8;
            u32x4 af[16];
            asm volatile(
                "global_load_dwordx4 %0, %16, off sc0 sc1\n\t"
                "global_load_dwordx4 %1, %16, off offset:64 sc0 sc1\n\t"
                "global_load_dwordx4 %2, %16, off offset:128 sc0 sc1\n\t"
                "global_load_dwordx4 %3, %16, off offset:192 sc0 sc1\n\t"
                "global_load_dwordx4 %4, %16, off offset:256 sc0 sc1\n\t"
                "global_load_dwordx4 %5, %16, off offset:320 sc0 sc1\n\t"
                "global_load_dwordx4 %6, %16, off offset:384 sc0 sc1\n\t"
                "global_load_dwordx4 %7, %16, off offset:448 sc0 sc1\n\t"
                "global_load_dwordx4 %8, %16, off offset:512 sc0 sc1\n\t"
                "global_load_dwordx4 %9, %16, off offset:576 sc0 sc1\n\t"
                "global_load_dwordx4 %10, %16, off offset:640 sc0 sc1\n\t"
                "global_load_dwordx4 %11, %16, off offset:704 sc0 sc1\n\t"
                "global_load_dwordx4 %12, %16, off offset:768 sc0 sc1\n\t"
                "global_load_dwordx4 %13, %16, off offset:832 sc0 sc1\n\t"
                "global_load_dwordx4 %14, %16, off offset:896 sc0 sc1\n\t"
                "global_load_dwordx4 %15, %16, off offset:960 sc0 sc1\n\t"
                "s_waitcnt vmcnt(0)"
                : "=&v"(af[0]), "=&v"(af[1]), "=&v"(af[2]), "=&v"(af[3]),
                  "=&v"(af[4]), "=&v"(af[5]), "=&v"(af[6]), "=&v"(af[7]),
                  "=&v"(af[8]), "=&v"(af[9]), "=&v"(af[10]), "=&v"(af[11]),
                  "=&v"(af[12]), "=&v"(af[13]), "=&v"(af[14]), "=&v"(af[15])
                : "v"(hrow)
                : "memory");
            __builtin_amdgcn_sched_barrier(0);

            // ---- MFMA chain, 2 independent accumulators
            union { u32x4 u; bf16x8 b; } ua, ub;
#pragma unroll
            for (int kk = 0; kk < 16; kk += 2) {
                ua.u = af[kk];
                acc0 = __builtin_amdgcn_mfma_f32_16x16x32_bf16(ua.b, wfrag[kk], acc0, 0, 0, 0);
                ub.u = af[kk + 1];
                acc1 = __builtin_amdgcn_mfma_f32_16x16x32_bf16(ub.b, wfrag[kk + 1], acc1, 0, 0, 0);
            }
        }
#pragma unroll
        for (int j = 0; j < 4; ++j) acc0[j] += acc1[j];

        // ---- gates to LDS (C layout: row=(lk*4+j)=batch, col=lr=gate col)
#pragma unroll
        for (int j = 0; j < 4; ++j) glds[w][lk * 4 + j][lr] = acc0[j];
        __syncthreads();

        // ---- elementwise LSTM cell
        float gi = glds[0][eb][ej];
        float gf = glds[1][eb][ej];
        float gg = glds[2][eb][ej];
        float go = glds[3][eb][ej];
        float i_ = 1.f / (1.f + __expf(-gi));
        float f_ = 1.f / (1.f + __expf(-gf));
        float g_ = tanhf(gg);
        float o_ = 1.f / (1.f + __expf(-go));
        c_reg = f_ * c_reg + i_ * g_;
        float hv = o_ * tanhf(c_reg);

        outp[(size_t)t * H_N] = hv;
        if (t == T_N - 1) {
            size_t bi = (size_t)(g * 16 + eb) * H_N + s * 16 + ej;
            hn[bi] = hv;
            cn[bi] = c_reg;
        }

        // ---- publish h (device-coherent) and signal
        ushort_t* rp = rp_base + ((size_t)(t & 1) * 2 + g) * (16 * 512);
        unsigned int hbits = (unsigned int)f2bf(hv);
        asm volatile("global_store_short %0, %1, off sc0 sc1\n\t"
                     "s_waitcnt vmcnt(0)"
                     :: "v"(rp), "v"(hbits) : "memory");
        __syncthreads();
        if (tid == 0)
            __hip_atomic_fetch_add(&cntg[t], 1, __ATOMIC_RELAXED,
                                   __HIP_MEMORY_SCOPE_AGENT);
    }
}

// ---------------------------------------------------------------------------
extern "C" void kernel_launch(void* const* d_in, const int* in_sizes, int n_in,
                              void* d_out, int out_size, void* d_ws, size_t ws_size,
                              hipStream_t stream) {
    (void)in_sizes; (void)n_in; (void)out_size; (void)ws_size;
    const float* x   = (const float*)d_in[0];
    const float* wih = (const float*)d_in[1];
    const float* whh = (const float*)d_in[2];
    const float* bih = (const float*)d_in[3];
    const float* bhh = (const float*)d_in[4];
    float* out = (float*)d_out;
    float* hn  = out + (size_t)B_N * T_N * H_N;
    float* cn  = hn + (size_t)B_N * H_N;

    char* ws = (char*)d_ws;
    // ws layout (all 256B-aligned):
    ushort_t* xg    = (ushort_t*)(ws);                       // 134217728 B
    ushort_t* xb    = (ushort_t*)(ws + 134217728);           //  33554432 B
    ushort_t* wihb  = (ushort_t*)(ws + 167772160);           //   2097152 B
    ushort_t* whhb  = (ushort_t*)(ws + 169869312);           //   2097152 B
    float*    bias  = (float*)   (ws + 171966464);           //      8192 B
    ushort_t* ring  = (ushort_t*)(ws + 171974656);           //     65536 B
    int*      cnt   = (int*)     (ws + 172040192);           //      8192 B

    prep_kernel<<<18432, 256, 0, stream>>>(x, wih, whh, bih, bhh,
                                           xb, wihb, whhb, bias, cnt);
    xg_gemm<<<2048, 512, 0, stream>>>(xb, wihb, bias, xg);
    lstm_rec<<<64, 256, 0, stream>>>(xg, whhb, ring, cnt, out, hn, cn);
}